// Round 11
// baseline (5106.679 us; speedup 1.0000x reference)
//
#include <hip/hip_runtime.h>
#include <hip/hip_bf16.h>
#include <cmath>

typedef unsigned short u16;
typedef __attribute__((ext_vector_type(8))) short short8;
typedef __attribute__((ext_vector_type(4))) float floatx4;

#define DEVI __device__ __forceinline__

constexpr int cV = 32000, cE = 512, cT = 64, cH = 1024, cZ = 128, cB = 64, cPAD = 31999, cTP1 = 65;
constexpr long long LOGP_SZ = 133120000LL;   // B*(T+1)*V f32 elems
constexpr long long AMAT_OFF = 130990080LL;  // logp tail: 260 frag-rows x 32 x 512 u16
constexpr long long WBOUT_OFF = 39936000LL;  // logp rows [1248,1760): 2000x32x512 u16 frag W
constexpr int SKIP_LO = 1248, SKIP_HI = 1760;

DEVI float b2f(u16 u) { return __uint_as_float(((unsigned)u) << 16); }
DEVI u16 f2b(float f) {
  unsigned u = __float_as_uint(f);
  unsigned r = u + 0x7FFFu + ((u >> 16) & 1u);
  return (u16)(r >> 16);
}
DEVI unsigned pk2(float lo, float hi) {
  __hip_bfloat162 t = __float22bfloat162_rn(make_float2(lo, hi));
  return *reinterpret_cast<unsigned*>(&t);
}
DEVI float sigm(float x) { return 1.f / (1.f + expf(-x)); }

DEVI short8 ldfragW(const float* __restrict__ p) {
  float4 x = *(const float4*)p, y = *(const float4*)(p + 4);
  union { unsigned u[4]; short8 s; } r;
  r.u[0] = pk2(x.x, x.y); r.u[1] = pk2(x.z, x.w);
  r.u[2] = pk2(y.x, y.y); r.u[3] = pk2(y.z, y.w);
  return r.s;
}

template <typename T>
DEVI short8 ldfrag(const T* __restrict__ p) {
  if constexpr (sizeof(T) == 2) return *(const short8*)(p);
  else return ldfragW((const float*)p);
}

template <int MAP>
DEVI int rmap(int r) {
  if constexpr (MAP == 1) return ((r & 3) << 10) | (r >> 2);  // n' -> g*1024+j
  else if constexpr (MAP == 2) return r & 63;                 // (t,b) row -> b
  else return r;
}

DEVI float dot_wf(const float* __restrict__ w, const float* __restrict__ s, int K) {
  float a0 = 0.f, a1 = 0.f, a2 = 0.f, a3 = 0.f;
#pragma unroll 4
  for (int k = 0; k < K; k += 8) {
    float4 p = *(const float4*)(w + k);
    float4 q = *(const float4*)(w + k + 4);
    a0 = fmaf(s[k + 0], p.x, a0); a1 = fmaf(s[k + 1], p.y, a1);
    a2 = fmaf(s[k + 2], p.z, a2); a3 = fmaf(s[k + 3], p.w, a3);
    a0 = fmaf(s[k + 4], q.x, a0); a1 = fmaf(s[k + 5], q.y, a1);
    a2 = fmaf(s[k + 6], q.z, a2); a3 = fmaf(s[k + 7], q.w, a3);
  }
  return (a0 + a1) + (a2 + a3);
}

__global__ __launch_bounds__(256) void k_zero(float* p, int n) {
  int i = blockIdx.x * 256 + threadIdx.x;
  if (i < n) p[i] = 0.f;
}

// ---------- generic MFMA GEMM: C[M,N] (+bias +D +C) = A[M,K] x B[N,K]^T ----------
// BFRAGKB>0: B is frag-linear bf16 with K/32 == BFRAGKB. CFRAG: C written frag-linear.
template <typename AT, typename BT, typename CT, int AMAP, int BMAP, bool ADDC,
          int BFRAGKB = 0, bool CFRAG = false>
__global__ __launch_bounds__(64) void k_gemm(
    const AT* __restrict__ A, int lda, const BT* __restrict__ B, int ldb,
    const float* __restrict__ bias, const float* __restrict__ Dm, int ldd,
    CT* __restrict__ C, int ldc, int K) {
  int nblk = blockIdx.x, mblk = blockIdx.y;
  int lane = threadIdx.x;
  int lr = lane & 15, kg = lane >> 4;
  const BT* Bp = B + (size_t)rmap<BMAP>(nblk * 16 + lr) * ldb + kg * 8;
  const AT* Ap[4];
#pragma unroll
  for (int mf = 0; mf < 4; mf++)
    Ap[mf] = A + (size_t)rmap<AMAP>(mblk * 64 + mf * 16 + lr) * lda + kg * 8;
  floatx4 acc[4];
#pragma unroll
  for (int mf = 0; mf < 4; mf++) acc[mf] = (floatx4){0.f, 0.f, 0.f, 0.f};
#pragma unroll 4
  for (int ks = 0; ks < K / 32; ks++) {
    short8 bv;
    if constexpr (BFRAGKB > 0)
      bv = *(const short8*)((const u16*)B + ((size_t)nblk * BFRAGKB + ks) * 512 + lane * 8);
    else
      bv = ldfrag(Bp + ks * 32);
#pragma unroll
    for (int mf = 0; mf < 4; mf++) {
      short8 av = ldfrag(Ap[mf] + ks * 32);
      acc[mf] = __builtin_amdgcn_mfma_f32_16x16x32_bf16(av, bv, acc[mf], 0, 0, 0);
    }
  }
  int n = nblk * 16 + lr;
  float bs = bias ? bias[n] : 0.f;
#pragma unroll
  for (int mf = 0; mf < 4; mf++) {
#pragma unroll
    for (int jj = 0; jj < 4; jj++) {
      int m = mblk * 64 + mf * 16 + kg * 4 + jj;
      float v = acc[mf][jj] + bs;
      if (Dm) v += Dm[(size_t)rmap<AMAP>(m) * ldd + n];
      if constexpr (CFRAG) {
        size_t fi = ((size_t)(m >> 4) * (ldc >> 5) + (n >> 5)) * 512 +
                    (size_t)((((n >> 3) & 3) * 16 + (m & 15)) * 8 + (n & 7));
        ((u16*)C)[fi] = f2b(v);
      } else {
        size_t ci = (size_t)m * ldc + n;
        if constexpr (ADDC) {
          if constexpr (sizeof(CT) == 2) v += b2f(C[ci]);
          else v += C[ci];
        }
        if constexpr (sizeof(CT) == 2) C[ci] = f2b(v);
        else C[ci] = v;
      }
    }
  }
}

// ---------- serial step: gates = G[t] + Wbig x h (all frag-linear); LSTM cell ----------
__global__ __launch_bounds__(64) void k_cell3(
    const u16* __restrict__ G,      // row-major [64 b][4096 n']
    const u16* __restrict__ Hf,     // frag [4 mfrag][32 kb][512]
    const u16* __restrict__ Wbf,    // frag [256 nfrag][32 kb][512]
    float* __restrict__ c,
    u16* __restrict__ outRM, int s1,
    u16* __restrict__ HfOut,
    u16* __restrict__ Afrag, int t) {
  int nb = blockIdx.x;  // 0..255
  int lane = threadIdx.x;
  int lr = lane & 15, kg = lane >> 4;
  floatx4 acc[4];
#pragma unroll
  for (int mf = 0; mf < 4; mf++) acc[mf] = (floatx4){0.f, 0.f, 0.f, 0.f};
#pragma unroll 8
  for (int ks = 0; ks < 32; ks++) {
    short8 bv = *(const short8*)(Wbf + ((size_t)nb * 32 + ks) * 512 + lane * 8);
#pragma unroll
    for (int mf = 0; mf < 4; mf++) {
      short8 av = *(const short8*)(Hf + ((size_t)mf * 32 + ks) * 512 + lane * 8);
      acc[mf] = __builtin_amdgcn_mfma_f32_16x16x32_bf16(av, bv, acc[mf], 0, 0, 0);
    }
  }
  __shared__ float lds[16][65];
#pragma unroll
  for (int mf = 0; mf < 4; mf++)
#pragma unroll
    for (int jj = 0; jj < 4; jj++)
      lds[lr][mf * 16 + kg * 4 + jj] = acc[mf][jj];
  __syncthreads();
  int b = lane;
  const u16* gp = G + (size_t)b * 4096 + nb * 16;
  float4 cc4 = *(const float4*)(c + (size_t)b * cH + nb * 4);
  float cin[4] = {cc4.x, cc4.y, cc4.z, cc4.w};
  float ncc[4];
  u16 hb[4];
#pragma unroll
  for (int a = 0; a < 4; a++) {
    float gi = lds[4 * a + 0][b] + b2f(gp[4 * a + 0]);
    float gf = lds[4 * a + 1][b] + b2f(gp[4 * a + 1]);
    float gg = lds[4 * a + 2][b] + b2f(gp[4 * a + 2]);
    float go = lds[4 * a + 3][b] + b2f(gp[4 * a + 3]);
    float cc = cin[a];
    cc = sigm(gf) * cc + sigm(gi) * tanhf(gg);
    float hh = sigm(go) * tanhf(cc);
    ncc[a] = cc;
    hb[a] = f2b(hh);
  }
  *(float4*)(c + (size_t)b * cH + nb * 4) = make_float4(ncc[0], ncc[1], ncc[2], ncc[3]);
  ushort4 hv = {hb[0], hb[1], hb[2], hb[3]};
  *(ushort4*)(outRM + (size_t)b * s1 + nb * 4) = hv;
  int j0 = nb * 4;
  size_t hidx = ((size_t)(b >> 4) * 32 + (j0 >> 5)) * 512 +
                (size_t)((((j0 >> 3) & 3) * 16 + (b & 15)) * 8 + (j0 & 7));
  *(ushort4*)(HfOut + hidx) = hv;
  if (Afrag) {
    int m = b * cTP1 + t;
    size_t aidx = ((size_t)(m >> 4) * 32 + (j0 >> 5)) * 512 +
                  (size_t)((((j0 >> 3) & 3) * 16 + (m & 15)) * 8 + (j0 & 7));
    *(ushort4*)(Afrag + aidx) = hv;
  }
}

// ---------- small prep kernels ----------
__global__ __launch_bounds__(256) void k_tr(const float* __restrict__ src, int ld,
                                            int R, float* __restrict__ dst) {
  __shared__ float tile[32][33];
  int c0 = blockIdx.x * 32, r0 = blockIdx.y * 32;
  int tx = threadIdx.x & 31, ty = threadIdx.x >> 5;
  for (int i = ty; i < 32; i += 8) tile[i][tx] = src[(size_t)(r0 + i) * ld + c0 + tx];
  __syncthreads();
  for (int i = ty; i < 32; i += 8) dst[(size_t)(c0 + i) * R + r0 + tx] = tile[tx][i];
}

__global__ __launch_bounds__(256) void k_gemv(const float* __restrict__ W, int ld,
                                              const float* __restrict__ x,
                                              const float* __restrict__ b,
                                              float* __restrict__ out, int K, int add) {
  int n = blockIdx.x * 256 + threadIdx.x;
  const float* w = W + (size_t)n * ld;
  float s = b ? b[n] : 0.f;
  for (int k = 0; k < K; k += 4) {
    float4 wv = *(const float4*)(w + k);
    float4 xv = *(const float4*)(x + k);
    s += wv.x * xv.x + wv.y * xv.y + wv.z * xv.z + wv.w * xv.w;
  }
  if (add) out[n] += s; else out[n] = s;
}

__global__ __launch_bounds__(256) void k_biasD(const float* __restrict__ bih,
                                               const float* __restrict__ bhh,
                                               const float* __restrict__ Wih,
                                               const float* __restrict__ u0,
                                               float* __restrict__ biasD) {
  int np = blockIdx.x * 256 + threadIdx.x;
  int src = ((np & 3) << 10) | (np >> 2);
  const float* w = Wih + (size_t)src * cH;
  float s = bih[src] + bhh[src];
  for (int k = 0; k < cH; k += 4) {
    float4 wv = *(const float4*)(w + k);
    float4 xv = *(const float4*)(u0 + k);
    s += wv.x * xv.x + wv.y * xv.y + wv.z * xv.z + wv.w * xv.w;
  }
  biasD[np] = s;
}

__global__ __launch_bounds__(256) void k_biasE(const float* __restrict__ bih,
                                               const float* __restrict__ bhh,
                                               float* __restrict__ biasE) {
  int np = blockIdx.x * 256 + threadIdx.x;
  int src = ((np & 3) << 10) | (np >> 2);
  biasE[np] = bih[src] + bhh[src];
}

// pack f32 [4096(perm n')][K] -> frag-linear bf16 (one wave per 16x32 frag)
__global__ __launch_bounds__(256) void k_packP(const float* __restrict__ W,
                                               u16* __restrict__ Wf, int K) {
  int g = blockIdx.x * 4 + (threadIdx.x >> 6);
  int l = threadIdx.x & 63;
  int KB = K >> 5;
  int nblk = g / KB, kb = g % KB;
  int np = nblk * 16 + (l & 15);
  int src = ((np & 3) << 10) | (np >> 2);
  const float* s = W + (size_t)src * K + kb * 32 + (l >> 4) * 8;
  *(short8*)(Wf + (size_t)g * 512 + l * 8) = ldfragW(s);
}

// out_W (f32 row-major [32000][1024]) -> frag-linear bf16
__global__ __launch_bounds__(256) void k_cvtW(const float* __restrict__ W,
                                              u16* __restrict__ Wf) {
  int g = blockIdx.x * 4 + (threadIdx.x >> 6);  // frag id 0..63999
  int l = threadIdx.x & 63;
  int nblk = g >> 5, kb = g & 31;
  const float* src = W + (size_t)(nblk * 16 + (l & 15)) * cH + kb * 32 + (l >> 4) * 8;
  *(short8*)(Wf + (size_t)g * 512 + l * 8) = ldfragW(src);
}

__global__ __launch_bounds__(256) void k_gather(const int* __restrict__ tok,
                                                const float* __restrict__ emb,
                                                u16* __restrict__ dst, int Tlen) {
  int r = blockIdx.x;
  int t = r >> 6, b = r & 63;
  const float* src = emb + (size_t)tok[b * Tlen + t] * cE;
  u16* d = dst + (size_t)r * cE;
  int tid = threadIdx.x;
  for (int k = tid; k < cE; k += 256) d[k] = f2b(src[k]);
}

// ---------- latent / z ----------
__global__ __launch_bounds__(256) void k_latent(
    const u16* __restrict__ encO, const float* __restrict__ cT2,
    const float* __restrict__ W, const float* __restrict__ bias,
    float* __restrict__ mulv, float* __restrict__ outp) {
  __shared__ float s[2 * cH];
  int b = blockIdx.x;
  int n = threadIdx.x;
  for (int k = n; k < cH; k += 256) {
    s[k] = b2f(encO[((size_t)b * cT + 63) * cH + k]);
    s[cH + k] = cT2[b * cH + k];
  }
  __syncthreads();
  float acc = bias[n] + dot_wf(W + (size_t)n * (2 * cH), s, 2 * cH);
  mulv[b * 256 + n] = acc;
  if (n < cZ)
    outp[LOGP_SZ + (size_t)b * cZ + n] = acc;
  else
    outp[LOGP_SZ + (size_t)cB * cZ + (size_t)b * cZ + (n - cZ)] = acc;
}

__global__ __launch_bounds__(256) void k_z(const float* __restrict__ mulv,
                                           const float* __restrict__ eps,
                                           u16* __restrict__ zbuf) {
  int i = blockIdx.x * 256 + threadIdx.x;
  if (i >= cB * cZ) return;
  int b = i >> 7, zi = i & 127;
  float mu = mulv[b * 256 + zi], lv = mulv[b * 256 + cZ + zi];
  zbuf[i] = f2b(mu + expf(0.5f * lv) * eps[i]);
}

// ---------- post-hoc: softmax + ctx ----------
__global__ __launch_bounds__(256) void k_sctx(
    const float* __restrict__ S, const int* __restrict__ enc_input,
    const u16* __restrict__ encO, u16* __restrict__ ctxH) {
  __shared__ float wat[cT];
  int tb = blockIdx.x;
  int b = tb & 63;
  int tid = threadIdx.x;
  if (tid < cT) {
    float sc = S[(size_t)tb * cT + tid];
    if (enc_input[b * cT + tid] == cPAD) sc = -INFINITY;
    float m = sc;
#pragma unroll
    for (int off = 32; off >= 1; off >>= 1) m = fmaxf(m, __shfl_xor(m, off));
    float p = expf(sc - m);
    float ssum = p;
#pragma unroll
    for (int off = 32; off >= 1; off >>= 1) ssum += __shfl_xor(ssum, off);
    wat[tid] = p / ssum;
  }
  __syncthreads();
#pragma unroll
  for (int p = 0; p < 4; p++) {
    int j = tid + p * 256;
    float s = 0.f;
    const u16* e = encO + ((size_t)b * cT) * cH + j;
#pragma unroll 8
    for (int t2 = 0; t2 < cT; t2++) s += wat[t2] * b2f(e[(size_t)t2 * cH]);
    ctxH[(size_t)tb * cH + j] = f2b(s);
  }
}

// ---------- post-hoc: kld + aux_c reductions ----------
__global__ __launch_bounds__(256) void k_scal_all(
    const float* __restrict__ priH, const float* __restrict__ infH,
    const u16* __restrict__ ctxH, const u16* __restrict__ auxH,
    const int* __restrict__ length, float* __restrict__ scal) {
  __shared__ float red[256];
  int tb = blockIdx.x;
  int t = tb >> 6, b = tb & 63;
  int tid = threadIdx.x;
  float r = 0.f;
  if (tid < cZ) {
    float pm = priH[(size_t)tb * 256 + tid], plv = priH[(size_t)tb * 256 + cZ + tid];
    float im = infH[(size_t)tb * 256 + tid], ilv = infH[(size_t)tb * 256 + cZ + tid];
    float d = im - pm;
    r = plv - ilv + expf(ilv - plv) + d * d * expf(-plv) - 1.f;
  }
  red[tid] = r;
  __syncthreads();
  for (int sft = 128; sft > 0; sft >>= 1) {
    if (tid < sft) red[tid] += red[tid + sft];
    __syncthreads();
  }
  if (tid == 0 && (length[b] + 1 > t)) atomicAdd(&scal[0], 0.5f * red[0]);
  __syncthreads();
  float r2 = 0.f;
#pragma unroll
  for (int p = 0; p < 4; p++) {
    int j = tid + p * 256;
    float d = b2f(ctxH[(size_t)tb * cH + j]) - b2f(auxH[(size_t)tb * cH + j]);
    r2 += d * d;
  }
  red[tid] = r2;
  __syncthreads();
  for (int sft = 128; sft > 0; sft >>= 1) {
    if (tid < sft) red[tid] += red[tid + sft];
    __syncthreads();
  }
  if (tid == 0) atomicAdd(&scal[1], red[0]);
}

__global__ void k_scal(const float* __restrict__ scal, float* __restrict__ outp) {
  if (threadIdx.x == 0) {
    outp[LOGP_SZ + 2 * cB * cZ] = scal[0];
    outp[LOGP_SZ + 2 * cB * cZ + 1] = scal[1];
  }
}

// copy Amat frag m-blocks [252,260) (256 KB) into d_ws
__global__ __launch_bounds__(256) void k_cpyA(const u16* __restrict__ src,
                                              u16* __restrict__ dst) {
  int i = blockIdx.x * 256 + threadIdx.x;  // 8192 x uint4
  ((uint4*)dst)[i] = ((const uint4*)(src + (size_t)252 * 32 * 512))[i];
}

// ---- output projection v4: N_BLK=64, half-K LDS panel (64KB), frag A+W ----
// grid 500, 512 thr (8 waves); wave = 64 rows x 64 cols per m-iter of 512 rows.
template <bool WFRAG>
__global__ __launch_bounds__(512) void k_logit4(
    const u16* __restrict__ Af, int fragBase,
    const u16* __restrict__ Wf, const float* __restrict__ Wraw,
    const float* __restrict__ bias, float* __restrict__ outp,
    int mStart, int mEnd, int storeLo, int storeHi, int skipLo, int skipHi) {
  __shared__ u16 wpan[32768];  // 64 frags [fr*16+kbl][512] = one K-half of 64 cols
  int nb = blockIdx.x;         // 0..499 (64 cols each)
  int tid = threadIdx.x;
  int wave = tid >> 6, lane = tid & 63;
  int lr = lane & 15, kg = lane >> 4;
  for (int m0 = mStart; m0 < mEnd; m0 += 512) {
    int mi = m0 + wave * 64;
    int mfg[4];
#pragma unroll
    for (int mf = 0; mf < 4; mf++) {
      int g = (mi >> 4) + mf;
      if (g > 259) g = 259;
      mfg[mf] = g - fragBase;
    }
    floatx4 acc[4][4];
#pragma unroll
    for (int mf = 0; mf < 4; mf++)
#pragma unroll
      for (int fr = 0; fr < 4; fr++) acc[mf][fr] = (floatx4){0.f, 0.f, 0.f, 0.f};
    for (int h = 0; h < 2; h++) {
      __syncthreads();  // all waves done with previous panel contents
      if constexpr (WFRAG) {
#pragma unroll
        for (int q = 0; q < 8; q++) {
          int idx = q * 4096 + tid * 8;  // u16 index
          int lf = idx >> 9, wi = idx & 511;
          int fr = lf >> 4, kbl = lf & 15;
          size_t g = (size_t)(nb * 4 + fr) * 32 + h * 16 + kbl;
          *(uint4*)(wpan + idx) = *(const uint4*)(Wf + g * 512 + wi);
        }
      } else {
        for (int f = wave; f < 64; f += 8) {
          int fr = f >> 4, kbl = f & 15;
          const float* src = Wraw + (size_t)(nb * 64 + fr * 16 + lr) * cH +
                             h * 512 + kbl * 32 + kg * 8;
          *(short8*)(wpan + (size_t)f * 512 + lane * 8) = ldfragW(src);
        }
      }
      __syncthreads();
#pragma unroll 4
      for (int ks = 0; ks < 16; ks++) {
        short8 bv[4];
#pragma unroll
        for (int fr = 0; fr < 4; fr++)
          bv[fr] = *(const short8*)(wpan + ((size_t)(fr * 16 + ks) * 512) + lane * 8);
#pragma unroll
        for (int mf = 0; mf < 4; mf++) {
          short8 av = *(const short8*)(Af + ((size_t)mfg[mf] * 32 + h * 16 + ks) * 512 + lane * 8);
#pragma unroll
          for (int fr = 0; fr < 4; fr++)
            acc[mf][fr] = __builtin_amdgcn_mfma_f32_16x16x32_bf16(av, bv[fr], acc[mf][fr], 0, 0, 0);
        }
      }
    }
#pragma unroll
    for (int mf = 0; mf < 4; mf++) {
#pragma unroll
      for (int fr = 0; fr < 4; fr++) {
        int n = nb * 64 + fr * 16 + lr;
        float bb = bias[n];
#pragma unroll
        for (int jj = 0; jj < 4; jj++) {
          int m = mi + mf * 16 + kg * 4 + jj;
          if (m >= storeLo && m < storeHi && !(m >= skipLo && m < skipHi))
            outp[(size_t)m * cV + n] = acc[mf][fr][jj] + bb;
        }
      }
    }
  }
}

// ---- row log-softmax, 2-pass online ----
__global__ __launch_bounds__(256) void k_lsm(float* __restrict__ outp) {
  __shared__ float wm_[4], ws_[4];
  __shared__ float blz;
  int m = blockIdx.x;
  int tid = threadIdx.x, lane = tid & 63, wid = tid >> 6;
  float4* rp4 = (float4*)(outp + (size_t)m * cV);
  float mx = -INFINITY, sm = 0.f;
  for (int n = tid; n < cV / 4; n += 256) {
    float4 v = rp4[n];
    float lm = fmaxf(fmaxf(v.x, v.y), fmaxf(v.z, v.w));
    float nm = fmaxf(mx, lm);
    sm = sm * expf(mx - nm) + expf(v.x - nm) + expf(v.y - nm) + expf(v.z - nm) + expf(v.w - nm);
    mx = nm;
  }
#pragma unroll
  for (int off = 32; off >= 1; off >>= 1) {
    float om = __shfl_xor(mx, off), os = __shfl_xor(sm, off);
    float nm = fmaxf(mx, om);
    sm = sm * expf(mx - nm) + os * expf(om - nm);
    mx = nm;
  }
  if (lane == 0) { wm_[wid] = mx; ws_[wid] = sm; }
  __syncthreads();
  if (tid == 0) {
    float M = fmaxf(fmaxf(wm_[0], wm_[1]), fmaxf(wm_[2], wm_[3]));
    float S = ws_[0] * expf(wm_[0] - M) + ws_[1] * expf(wm_[1] - M) +
              ws_[2] * expf(wm_[2] - M) + ws_[3] * expf(wm_[3] - M);
    blz = M + logf(S);
  }
  __syncthreads();
  float lz = blz;
  for (int n = tid; n < cV / 4; n += 256) {
    float4 v = rp4[n];
    v.x -= lz; v.y -= lz; v.z -= lz; v.w -= lz;
    rp4[n] = v;
  }
}

extern "C" void kernel_launch(void* const* d_in, const int* in_sizes, int n_in,
                              void* d_out, int out_size, void* d_ws, size_t ws_size,
                              hipStream_t stream) {
  (void)in_sizes; (void)n_in; (void)out_size; (void)ws_size;
  const int* enc_input  = (const int*)d_in[0];
  const int* dec_input  = (const int*)d_in[1];
  const int* length     = (const int*)d_in[2];
  const float* eps      = (const float*)d_in[3];
  const float* enc_emb  = (const float*)d_in[4];
  const float* enc_Wih  = (const float*)d_in[5];
  const float* enc_Whh  = (const float*)d_in[6];
  const float* enc_bih  = (const float*)d_in[7];
  const float* enc_bhh  = (const float*)d_in[8];
  const float* latent_W = (const float*)d_in[9];
  const float* latent_b = (const float*)d_in[10];
  const float* dec_emb  = (const float*)d_in[11];
  const float* attn_W   = (const float*)d_in[12];
  const float* attn_b   = (const float*)d_in[13];
  const float* comb_W   = (const float*)d_in[14];
  const float* comb_b   = (const float*)d_in[15];
  const float* dec_Wih  = (const float*)d_in[16];
  const float* dec_Whh  = (const float*)d_in[17];
  const float* dec_bih  = (const float*)d_in[18];
  const float* dec_bhh  = (const float*)d_in[19];
  const float* pri_W    = (const float*)d_in[20];
  const float* pri_b    = (const float*)d_in[21];
  const float* inf_W    = (const float*)d_in[22];
  const float* inf_b    = (const float*)d_in[23];
  const float* aux_W    = (const float*)d_in[24];
  const float* aux_b    = (const float*)d_in[25];
  const float* out_W    = (const float*)d_in[26];
  const float* out_b    = (const float*)d_in[27];
  float* outp = (float*)d_out;
  float* outF = outp;

  // ---- scratch layout in logp head (dead before k_logit4) ----
  size_t off = 0;
  float* c_enc = outF + off; off += 65536;
  float* c_dec = outF + off; off += 65536;
  float* scal  = outF + off; off += 4;
  off += 60;
  u16* HfEncA = (u16*)(outF + off); off += 32768;
  u16* HfDecA = (u16*)(outF + off); off += 32768;
  u16* Hh     = (u16*)(outF + off); off += 66 * 32768;  // row-major [66][64][1024]
  size_t zeroSpan = 229440;  // c_enc..Hh[0] inclusive
  u16* HfEncB = (u16*)(outF + off); off += 32768;
  u16* HfDecB = (u16*)(outF + off); off += 32768;
  u16* encO  = (u16*)(outF + off); off += 2097152;
  u16* Xenc  = (u16*)(outF + off); off += 1048576;
  u16* Xdec  = (u16*)(outF + off); off += 1064960;
  u16* zbuf  = (u16*)(outF + off); off += 4096;
  float* mulv  = outF + off; off += 16384;
  float* biasE = outF + off; off += 4096;
  float* biasD = outF + off; off += 4096;
  float* tmp1  = outF + off; off += 1024;
  float* u0    = outF + off; off += 1024;
  float* WcxT  = outF + off; off += 524288;
  float* WczT  = outF + off; off += 131072;
  float* wPmT  = outF + off; off += 131072;
  float* auxWT = outF + off; off += 131072;
  float* M1    = outF + off; off += 131072;
  float* WfT   = outF + off; off += 1048576;
  u16* WhhEpF = (u16*)(outF + off); off += 2097152;  // frag
  u16* WbigF  = (u16*)(outF + off); off += 2097152;  // frag
  u16* C1f    = (u16*)(outF + off); off += 1048576;  // frag KB=16
  u16* C2f    = (u16*)(outF + off); off += 262144;   // frag KB=4
  u16* WihEf  = (u16*)(outF + off); off += 1048576;  // frag KB=16
  u16* Genc  = (u16*)(outF + off); off += 8388608;
  u16* Gdec  = (u16*)(outF + off); off += 8519680;
  float* priH = outF + off; off += 1064960;
  float* infH = outF + off; off += 1064960;
  float* S    = outF + off; off += 266240;
  u16* ctxH  = (u16*)(outF + off); off += 2129920;
  u16* auxH  = (u16*)(outF + off); off += 2129920;  // ends ~38.88M < 39.94M
  u16* Wf   = (u16*)(outF + WBOUT_OFF);   // frag bf16 out_W: logp rows [1248,1760)
  u16* Amat = (u16*)(outF + AMAT_OFF);    // frag bf16 A: logp tail
  u16* wsA = (u16*)d_ws;

  // ---- prep ----
  k_cvtW<<<16000, 256, 0, stream>>>(out_W, Wf);
  k_tr<<<dim3(16, 32), 256, 0, stream>>>(comb_W, 1792, 1024, WcxT);
  k_tr<<<dim3(4, 32), 256, 0, stream>>>(comb_W + 1664, 1792, 1024, WczT);
  k_tr<<<dim3(32, 4), 256, 0, stream>>>(pri_W, 1024, 128, wPmT);
  k_tr<<<dim3(4, 32), 256, 0, stream>>>(aux_W, 128, 1024, auxWT);
  k_gemv<<<4, 256, 0, stream>>>(aux_W, 128, pri_b, aux_b, tmp1, 128, 0);
  k_gemv<<<4, 256, 0, stream>>>(comb_W + 512, 1792, tmp1, comb_b, u0, 1024, 0);
  k_gemv<<<4, 256, 0, stream>>>(comb_W + 1536, 1792, pri_b, nullptr, u0, 128, 1);
  k_biasE<<<16, 256, 0, stream>>>(enc_bih, enc_bhh, biasE);
  k_biasD<<<16, 256, 0, stream>>>(dec_bih, dec_bhh, dec_Wih, u0, biasD);
  k_packP<<<2048, 256, 0, stream>>>(enc_Whh, WhhEpF, 1024);
  k_packP<<<1024, 256, 0, stream>>>(enc_Wih, WihEf, 512);
  k_gather<<<cT * cB, 256, 0, stream>>>(enc_input, enc_emb, Xenc, cT);
  k_gather<<<cTP1 * cB, 256, 0, stream>>>(dec_input, dec_emb, Xdec, cTP1);
  k_zero<<<(int)((zeroSpan + 255) / 256), 256, 0, stream>>>(c_enc, (int)zeroSpan);

  // ---- weight composition ----
  k_gemm<float, float, float, 0, 0, false><<<dim3(8, 16), 64, 0, stream>>>(
      comb_W + 512, 1792, auxWT, 1024, nullptr, comb_W + 1536, 1792, M1, 128, 1024);
  k_gemm<float, float, float, 0, 0, false><<<dim3(64, 16), 64, 0, stream>>>(
      wPmT, 128, M1, 128, nullptr, nullptr, 0, WfT, 1024, 128);
  k_gemm<float, float, u16, 1, 0, false, 0, true><<<dim3(64, 64), 64, 0, stream>>>(
      dec_Wih, 1024, WfT, 1024, nullptr, dec_Whh, 1024, WbigF, 1024, 1024);
  k_gemm<float, float, u16, 1, 0, false, 0, true><<<dim3(32, 64), 64, 0, stream>>>(
      dec_Wih, 1024, WcxT, 1024, nullptr, nullptr, 0, C1f, 512, 1024);
  k_gemm<float, float, u16, 1, 0, false, 0, true><<<dim3(8, 64), 64, 0, stream>>>(
      dec_Wih, 1024, WczT, 1024, nullptr, nullptr, 0, C2f, 128, 1024);
  k_gemm<u16, u16, u16, 0, 0, false, 16, false><<<dim3(256, 64), 64, 0, stream>>>(
      Xenc, 512, WihEf, 512, biasE, nullptr, 0, Genc, 4096, 512);

  // ---- encoder loop ----
  for (int t = 0; t < cT; t++) {
    const u16* hin = (t & 1) ? HfEncB : HfEncA;
    u16* hout = (t & 1) ? HfEncA : HfEncB;
    k_cell3<<<256, 64, 0, stream>>>(Genc + (size_t)t * cB * 4096, hin, WhhEpF,
                                    c_enc, encO + (size_t)t * cH, cT * cH,
                                    hout, nullptr, 0);
  }
  k_latent<<<cB, 256, 0, stream>>>(encO, c_enc, latent_W, latent_b, mulv, outp);
  k_z<<<(cB * cZ + 255) / 256, 256, 0, stream>>>(mulv, eps, zbuf);

  // ---- Gdec ----
  k_gemm<u16, u16, u16, 0, 0, false, 16, false><<<dim3(256, 65), 64, 0, stream>>>(
      Xdec, 512, C1f, 512, biasD, nullptr, 0, Gdec, 4096, 512);
  k_gemm<u16, u16, u16, 2, 0, true, 4, false><<<dim3(256, 65), 64, 0, stream>>>(
      zbuf, 128, C2f, 128, nullptr, nullptr, 0, Gdec, 4096, 128);

  // ---- decoder loop ----
  for (int t = 0; t < cTP1; t++) {
    const u16* hin = (t & 1) ? HfDecB : HfDecA;
    u16* hout = (t & 1) ? HfDecA : HfDecB;
    k_cell3<<<256, 64, 0, stream>>>(Gdec + (size_t)t * cB * 4096, hin, WbigF,
                                    c_dec, Hh + (size_t)(t + 1) * cB * cH, cH,
                                    hout, Amat, t);
  }

  // ---- post-hoc batched math ----
  k_gemm<u16, float, float, 0, 0, false><<<dim3(16, 65), 64, 0, stream>>>(
      Hh, 1024, pri_W, 1024, pri_b, nullptr, 0, priH, 256, 1024);
  k_gemm<u16, float, float, 0, 0, false><<<dim3(4, 65), 64, 0, stream>>>(
      Xdec, 512, attn_W, 1536, attn_b, nullptr, 0, S, 64, 512);
  k_gemm<u16, float, float, 0, 0, true><<<dim3(4, 65), 64, 0, stream>>>(
      Hh, 1024, attn_W + 512, 1536, nullptr, nullptr, 0, S, 64, 1024);
  k_sctx<<<cTP1 * cB, 256, 0, stream>>>(S, enc_input, encO, ctxH);
  k_gemm<u16, float, float, 0, 0, false><<<dim3(16, 65), 64, 0, stream>>>(
      Hh, 1024, inf_W, 2048, inf_b, nullptr, 0, infH, 256, 1024);
  k_gemm<u16, float, float, 0, 0, true><<<dim3(16, 65), 64, 0, stream>>>(
      ctxH, 1024, inf_W + 1024, 2048, nullptr, nullptr, 0, infH, 256, 1024);
  k_gemm<float, float, u16, 0, 0, false><<<dim3(64, 65), 64, 0, stream>>>(
      priH, 256, aux_W, 128, aux_b, nullptr, 0, auxH, 1024, 128);
  k_scal_all<<<cTP1 * cB, 256, 0, stream>>>(priH, infH, ctxH, auxH, length, scal);
  k_scal<<<1, 64, 0, stream>>>(scal, outp);

  // ---- output projection + log-softmax ----
  k_cpyA<<<32, 256, 0, stream>>>(Amat, wsA);
  // L1: all rows, store m<4093 minus the Wf stripe; frag A + frag W panel
  k_logit4<true><<<500, 512, 0, stream>>>(Amat, 0, Wf, nullptr, out_b, outp,
                                          0, 4096, 0, 4093, SKIP_LO, SKIP_HI);
  // L2a: the stripe rows, W streamed from f32 original
  k_logit4<false><<<500, 512, 0, stream>>>(Amat, 0, nullptr, out_W, out_b, outp,
                                           SKIP_LO, SKIP_HI, SKIP_LO, SKIP_HI, 0, 0);
  // L2b: tail rows from the d_ws frag copy
  k_logit4<false><<<500, 512, 0, stream>>>(wsA, 252, nullptr, out_W, out_b, outp,
                                           4032, 4160, 4093, 4160, 0, 0);
  k_lsm<<<cB * cTP1, 256, 0, stream>>>(outp);
}

// Round 12
// 4699.027 us; speedup vs baseline: 1.0868x; 1.0868x over previous
//
#include <hip/hip_runtime.h>
#include <hip/hip_bf16.h>
#include <cmath>

typedef unsigned short u16;
typedef __attribute__((ext_vector_type(8))) short short8;
typedef __attribute__((ext_vector_type(4))) float floatx4;

#define DEVI __device__ __forceinline__

constexpr int cV = 32000, cE = 512, cT = 64, cH = 1024, cZ = 128, cB = 64, cPAD = 31999, cTP1 = 65;
constexpr long long LOGP_SZ = 133120000LL;   // B*(T+1)*V f32 elems
constexpr long long AMAT_OFF = 130990080LL;  // logp tail: 260 frag-rows x 32 x 512 u16
constexpr long long WBOUT_OFF = 39936000LL;  // logp rows [1248,1760): frag bf16 out_W
constexpr int SKIP_LO = 1248, SKIP_HI = 1760;

DEVI float b2f(u16 u) { return __uint_as_float(((unsigned)u) << 16); }
DEVI u16 f2b(float f) {
  unsigned u = __float_as_uint(f);
  unsigned r = u + 0x7FFFu + ((u >> 16) & 1u);
  return (u16)(r >> 16);
}
DEVI unsigned pk2(float lo, float hi) {
  __hip_bfloat162 t = __float22bfloat162_rn(make_float2(lo, hi));
  return *reinterpret_cast<unsigned*>(&t);
}
DEVI float sigm(float x) { return 1.f / (1.f + expf(-x)); }

DEVI short8 ldfragW(const float* __restrict__ p) {
  float4 x = *(const float4*)p, y = *(const float4*)(p + 4);
  union { unsigned u[4]; short8 s; } r;
  r.u[0] = pk2(x.x, x.y); r.u[1] = pk2(x.z, x.w);
  r.u[2] = pk2(y.x, y.y); r.u[3] = pk2(y.z, y.w);
  return r.s;
}

template <typename T>
DEVI short8 ldfrag(const T* __restrict__ p) {
  if constexpr (sizeof(T) == 2) return *(const short8*)(p);
  else return ldfragW((const float*)p);
}

template <int MAP>
DEVI int rmap(int r) {
  if constexpr (MAP == 1) return ((r & 3) << 10) | (r >> 2);  // n' -> g*1024+j
  else if constexpr (MAP == 2) return r & 63;                 // (t,b) row -> b
  else return r;
}

DEVI float dot_wf(const float* __restrict__ w, const float* __restrict__ s, int K) {
  float a0 = 0.f, a1 = 0.f, a2 = 0.f, a3 = 0.f;
#pragma unroll 4
  for (int k = 0; k < K; k += 8) {
    float4 p = *(const float4*)(w + k);
    float4 q = *(const float4*)(w + k + 4);
    a0 = fmaf(s[k + 0], p.x, a0); a1 = fmaf(s[k + 1], p.y, a1);
    a2 = fmaf(s[k + 2], p.z, a2); a3 = fmaf(s[k + 3], p.w, a3);
    a0 = fmaf(s[k + 4], q.x, a0); a1 = fmaf(s[k + 5], q.y, a1);
    a2 = fmaf(s[k + 6], q.z, a2); a3 = fmaf(s[k + 7], q.w, a3);
  }
  return (a0 + a1) + (a2 + a3);
}

__global__ __launch_bounds__(256) void k_zero(float* p, int n) {
  int i = blockIdx.x * 256 + threadIdx.x;
  if (i < n) p[i] = 0.f;
}

// ---------- generic MFMA GEMM: C[M,N] (+bias +D +C) = A[M,K] x B[N,K]^T ----------
template <typename AT, typename BT, typename CT, int AMAP, int BMAP, bool ADDC,
          int BFRAGKB = 0, bool CFRAG = false>
__global__ __launch_bounds__(64) void k_gemm(
    const AT* __restrict__ A, int lda, const BT* __restrict__ B, int ldb,
    const float* __restrict__ bias, const float* __restrict__ Dm, int ldd,
    CT* __restrict__ C, int ldc, int K) {
  int nblk = blockIdx.x, mblk = blockIdx.y;
  int lane = threadIdx.x;
  int lr = lane & 15, kg = lane >> 4;
  const BT* Bp = B + (size_t)rmap<BMAP>(nblk * 16 + lr) * ldb + kg * 8;
  const AT* Ap[4];
#pragma unroll
  for (int mf = 0; mf < 4; mf++)
    Ap[mf] = A + (size_t)rmap<AMAP>(mblk * 64 + mf * 16 + lr) * lda + kg * 8;
  floatx4 acc[4];
#pragma unroll
  for (int mf = 0; mf < 4; mf++) acc[mf] = (floatx4){0.f, 0.f, 0.f, 0.f};
#pragma unroll 4
  for (int ks = 0; ks < K / 32; ks++) {
    short8 bv;
    if constexpr (BFRAGKB > 0)
      bv = *(const short8*)((const u16*)B + ((size_t)nblk * BFRAGKB + ks) * 512 + lane * 8);
    else
      bv = ldfrag(Bp + ks * 32);
#pragma unroll
    for (int mf = 0; mf < 4; mf++) {
      short8 av = ldfrag(Ap[mf] + ks * 32);
      acc[mf] = __builtin_amdgcn_mfma_f32_16x16x32_bf16(av, bv, acc[mf], 0, 0, 0);
    }
  }
  int n = nblk * 16 + lr;
  float bs = bias ? bias[n] : 0.f;
#pragma unroll
  for (int mf = 0; mf < 4; mf++) {
#pragma unroll
    for (int jj = 0; jj < 4; jj++) {
      int m = mblk * 64 + mf * 16 + kg * 4 + jj;
      float v = acc[mf][jj] + bs;
      if (Dm) v += Dm[(size_t)rmap<AMAP>(m) * ldd + n];
      if constexpr (CFRAG) {
        size_t fi = ((size_t)(m >> 4) * (ldc >> 5) + (n >> 5)) * 512 +
                    (size_t)((((n >> 3) & 3) * 16 + (m & 15)) * 8 + (n & 7));
        ((u16*)C)[fi] = f2b(v);
      } else {
        size_t ci = (size_t)m * ldc + n;
        if constexpr (ADDC) {
          if constexpr (sizeof(CT) == 2) v += b2f(C[ci]);
          else v += C[ci];
        }
        if constexpr (sizeof(CT) == 2) C[ci] = f2b(v);
        else C[ci] = v;
      }
    }
  }
}

// ---------- serial step: gates = G[t] + Wbig x h (all frag-linear); LSTM cell ----------
__global__ __launch_bounds__(64) void k_cell3(
    const u16* __restrict__ G,      // row-major [64 b][4096 n']
    const u16* __restrict__ Hf,     // frag [4 mfrag][32 kb][512]
    const u16* __restrict__ Wbf,    // frag [256 nfrag][32 kb][512]
    float* __restrict__ c,
    u16* __restrict__ outRM, int s1,
    u16* __restrict__ HfOut,
    u16* __restrict__ Afrag, int t) {
  int nb = blockIdx.x;  // 0..255
  int lane = threadIdx.x;
  int lr = lane & 15, kg = lane >> 4;
  floatx4 acc[4];
#pragma unroll
  for (int mf = 0; mf < 4; mf++) acc[mf] = (floatx4){0.f, 0.f, 0.f, 0.f};
#pragma unroll 8
  for (int ks = 0; ks < 32; ks++) {
    short8 bv = *(const short8*)(Wbf + ((size_t)nb * 32 + ks) * 512 + lane * 8);
#pragma unroll
    for (int mf = 0; mf < 4; mf++) {
      short8 av = *(const short8*)(Hf + ((size_t)mf * 32 + ks) * 512 + lane * 8);
      acc[mf] = __builtin_amdgcn_mfma_f32_16x16x32_bf16(av, bv, acc[mf], 0, 0, 0);
    }
  }
  __shared__ float lds[16][65];
#pragma unroll
  for (int mf = 0; mf < 4; mf++)
#pragma unroll
    for (int jj = 0; jj < 4; jj++)
      lds[lr][mf * 16 + kg * 4 + jj] = acc[mf][jj];
  __syncthreads();
  int b = lane;
  const u16* gp = G + (size_t)b * 4096 + nb * 16;
  float4 cc4 = *(const float4*)(c + (size_t)b * cH + nb * 4);
  float cin[4] = {cc4.x, cc4.y, cc4.z, cc4.w};
  float ncc[4];
  u16 hb[4];
#pragma unroll
  for (int a = 0; a < 4; a++) {
    float gi = lds[4 * a + 0][b] + b2f(gp[4 * a + 0]);
    float gf = lds[4 * a + 1][b] + b2f(gp[4 * a + 1]);
    float gg = lds[4 * a + 2][b] + b2f(gp[4 * a + 2]);
    float go = lds[4 * a + 3][b] + b2f(gp[4 * a + 3]);
    float cc = cin[a];
    cc = sigm(gf) * cc + sigm(gi) * tanhf(gg);
    float hh = sigm(go) * tanhf(cc);
    ncc[a] = cc;
    hb[a] = f2b(hh);
  }
  *(float4*)(c + (size_t)b * cH + nb * 4) = make_float4(ncc[0], ncc[1], ncc[2], ncc[3]);
  ushort4 hv = {hb[0], hb[1], hb[2], hb[3]};
  *(ushort4*)(outRM + (size_t)b * s1 + nb * 4) = hv;
  int j0 = nb * 4;
  size_t hidx = ((size_t)(b >> 4) * 32 + (j0 >> 5)) * 512 +
                (size_t)((((j0 >> 3) & 3) * 16 + (b & 15)) * 8 + (j0 & 7));
  *(ushort4*)(HfOut + hidx) = hv;
  if (Afrag) {
    int m = b * cTP1 + t;
    size_t aidx = ((size_t)(m >> 4) * 32 + (j0 >> 5)) * 512 +
                  (size_t)((((j0 >> 3) & 3) * 16 + (m & 15)) * 8 + (j0 & 7));
    *(ushort4*)(Afrag + aidx) = hv;
  }
}

// ---------- small prep kernels ----------
__global__ __launch_bounds__(256) void k_tr(const float* __restrict__ src, int ld,
                                            int R, float* __restrict__ dst) {
  __shared__ float tile[32][33];
  int c0 = blockIdx.x * 32, r0 = blockIdx.y * 32;
  int tx = threadIdx.x & 31, ty = threadIdx.x >> 5;
  for (int i = ty; i < 32; i += 8) tile[i][tx] = src[(size_t)(r0 + i) * ld + c0 + tx];
  __syncthreads();
  for (int i = ty; i < 32; i += 8) dst[(size_t)(c0 + i) * R + r0 + tx] = tile[tx][i];
}

__global__ __launch_bounds__(256) void k_gemv(const float* __restrict__ W, int ld,
                                              const float* __restrict__ x,
                                              const float* __restrict__ b,
                                              float* __restrict__ out, int K, int add) {
  int n = blockIdx.x * 256 + threadIdx.x;
  const float* w = W + (size_t)n * ld;
  float s = b ? b[n] : 0.f;
  for (int k = 0; k < K; k += 4) {
    float4 wv = *(const float4*)(w + k);
    float4 xv = *(const float4*)(x + k);
    s += wv.x * xv.x + wv.y * xv.y + wv.z * xv.z + wv.w * xv.w;
  }
  if (add) out[n] += s; else out[n] = s;
}

__global__ __launch_bounds__(256) void k_biasD(const float* __restrict__ bih,
                                               const float* __restrict__ bhh,
                                               const float* __restrict__ Wih,
                                               const float* __restrict__ u0,
                                               float* __restrict__ biasD) {
  int np = blockIdx.x * 256 + threadIdx.x;
  int src = ((np & 3) << 10) | (np >> 2);
  const float* w = Wih + (size_t)src * cH;
  float s = bih[src] + bhh[src];
  for (int k = 0; k < cH; k += 4) {
    float4 wv = *(const float4*)(w + k);
    float4 xv = *(const float4*)(u0 + k);
    s += wv.x * xv.x + wv.y * xv.y + wv.z * xv.z + wv.w * xv.w;
  }
  biasD[np] = s;
}

__global__ __launch_bounds__(256) void k_biasE(const float* __restrict__ bih,
                                               const float* __restrict__ bhh,
                                               float* __restrict__ biasE) {
  int np = blockIdx.x * 256 + threadIdx.x;
  int src = ((np & 3) << 10) | (np >> 2);
  biasE[np] = bih[src] + bhh[src];
}

// pack f32 [4096(perm n')][K] -> frag-linear bf16 (one wave per 16x32 frag)
__global__ __launch_bounds__(256) void k_packP(const float* __restrict__ W,
                                               u16* __restrict__ Wf, int K) {
  int g = blockIdx.x * 4 + (threadIdx.x >> 6);
  int l = threadIdx.x & 63;
  int KB = K >> 5;
  int nblk = g / KB, kb = g % KB;
  int np = nblk * 16 + (l & 15);
  int src = ((np & 3) << 10) | (np >> 2);
  const float* s = W + (size_t)src * K + kb * 32 + (l >> 4) * 8;
  *(short8*)(Wf + (size_t)g * 512 + l * 8) = ldfragW(s);
}

// out_W (f32 row-major [32000][1024]) -> frag-linear bf16
__global__ __launch_bounds__(256) void k_cvtW(const float* __restrict__ W,
                                              u16* __restrict__ Wf) {
  int g = blockIdx.x * 4 + (threadIdx.x >> 6);  // frag id 0..63999
  int l = threadIdx.x & 63;
  int nblk = g >> 5, kb = g & 31;
  const float* src = W + (size_t)(nblk * 16 + (l & 15)) * cH + kb * 32 + (l >> 4) * 8;
  *(short8*)(Wf + (size_t)g * 512 + l * 8) = ldfragW(src);
}

__global__ __launch_bounds__(256) void k_gather(const int* __restrict__ tok,
                                                const float* __restrict__ emb,
                                                u16* __restrict__ dst, int Tlen) {
  int r = blockIdx.x;
  int t = r >> 6, b = r & 63;
  const float* src = emb + (size_t)tok[b * Tlen + t] * cE;
  u16* d = dst + (size_t)r * cE;
  int tid = threadIdx.x;
  for (int k = tid; k < cE; k += 256) d[k] = f2b(src[k]);
}

// ---------- latent / z ----------
__global__ __launch_bounds__(256) void k_latent(
    const u16* __restrict__ encO, const float* __restrict__ cT2,
    const float* __restrict__ W, const float* __restrict__ bias,
    float* __restrict__ mulv, float* __restrict__ outp) {
  __shared__ float s[2 * cH];
  int b = blockIdx.x;
  int n = threadIdx.x;
  for (int k = n; k < cH; k += 256) {
    s[k] = b2f(encO[((size_t)b * cT + 63) * cH + k]);
    s[cH + k] = cT2[b * cH + k];
  }
  __syncthreads();
  float acc = bias[n] + dot_wf(W + (size_t)n * (2 * cH), s, 2 * cH);
  mulv[b * 256 + n] = acc;
  if (n < cZ)
    outp[LOGP_SZ + (size_t)b * cZ + n] = acc;
  else
    outp[LOGP_SZ + (size_t)cB * cZ + (size_t)b * cZ + (n - cZ)] = acc;
}

__global__ __launch_bounds__(256) void k_z(const float* __restrict__ mulv,
                                           const float* __restrict__ eps,
                                           u16* __restrict__ zbuf) {
  int i = blockIdx.x * 256 + threadIdx.x;
  if (i >= cB * cZ) return;
  int b = i >> 7, zi = i & 127;
  float mu = mulv[b * 256 + zi], lv = mulv[b * 256 + cZ + zi];
  zbuf[i] = f2b(mu + expf(0.5f * lv) * eps[i]);
}

// ---------- post-hoc: softmax + ctx ----------
__global__ __launch_bounds__(256) void k_sctx(
    const float* __restrict__ S, const int* __restrict__ enc_input,
    const u16* __restrict__ encO, u16* __restrict__ ctxH) {
  __shared__ float wat[cT];
  int tb = blockIdx.x;
  int b = tb & 63;
  int tid = threadIdx.x;
  if (tid < cT) {
    float sc = S[(size_t)tb * cT + tid];
    if (enc_input[b * cT + tid] == cPAD) sc = -INFINITY;
    float m = sc;
#pragma unroll
    for (int off = 32; off >= 1; off >>= 1) m = fmaxf(m, __shfl_xor(m, off));
    float p = expf(sc - m);
    float ssum = p;
#pragma unroll
    for (int off = 32; off >= 1; off >>= 1) ssum += __shfl_xor(ssum, off);
    wat[tid] = p / ssum;
  }
  __syncthreads();
#pragma unroll
  for (int p = 0; p < 4; p++) {
    int j = tid + p * 256;
    float s = 0.f;
    const u16* e = encO + ((size_t)b * cT) * cH + j;
#pragma unroll 8
    for (int t2 = 0; t2 < cT; t2++) s += wat[t2] * b2f(e[(size_t)t2 * cH]);
    ctxH[(size_t)tb * cH + j] = f2b(s);
  }
}

// ---------- post-hoc: kld + aux_c reductions ----------
__global__ __launch_bounds__(256) void k_scal_all(
    const float* __restrict__ priH, const float* __restrict__ infH,
    const u16* __restrict__ ctxH, const u16* __restrict__ auxH,
    const int* __restrict__ length, float* __restrict__ scal) {
  __shared__ float red[256];
  int tb = blockIdx.x;
  int t = tb >> 6, b = tb & 63;
  int tid = threadIdx.x;
  float r = 0.f;
  if (tid < cZ) {
    float pm = priH[(size_t)tb * 256 + tid], plv = priH[(size_t)tb * 256 + cZ + tid];
    float im = infH[(size_t)tb * 256 + tid], ilv = infH[(size_t)tb * 256 + cZ + tid];
    float d = im - pm;
    r = plv - ilv + expf(ilv - plv) + d * d * expf(-plv) - 1.f;
  }
  red[tid] = r;
  __syncthreads();
  for (int sft = 128; sft > 0; sft >>= 1) {
    if (tid < sft) red[tid] += red[tid + sft];
    __syncthreads();
  }
  if (tid == 0 && (length[b] + 1 > t)) atomicAdd(&scal[0], 0.5f * red[0]);
  __syncthreads();
  float r2 = 0.f;
#pragma unroll
  for (int p = 0; p < 4; p++) {
    int j = tid + p * 256;
    float d = b2f(ctxH[(size_t)tb * cH + j]) - b2f(auxH[(size_t)tb * cH + j]);
    r2 += d * d;
  }
  red[tid] = r2;
  __syncthreads();
  for (int sft = 128; sft > 0; sft >>= 1) {
    if (tid < sft) red[tid] += red[tid + sft];
    __syncthreads();
  }
  if (tid == 0) atomicAdd(&scal[1], red[0]);
}

__global__ void k_scal(const float* __restrict__ scal, float* __restrict__ outp) {
  if (threadIdx.x == 0) {
    outp[LOGP_SZ + 2 * cB * cZ] = scal[0];
    outp[LOGP_SZ + 2 * cB * cZ + 1] = scal[1];
  }
}

// copy Amat frag m-blocks [252,260) (256 KB) into d_ws
__global__ __launch_bounds__(256) void k_cpyA(const u16* __restrict__ src,
                                              u16* __restrict__ dst) {
  int i = blockIdx.x * 256 + threadIdx.x;  // 8192 x uint4
  ((uint4*)dst)[i] = ((const uint4*)(src + (size_t)252 * 32 * 512))[i];
}

// ---- output projection (round-10 proven): frag A + 64KB frag W panel staged ONCE ----
// grid 1000 (N/32), 512 thr (8 waves); wave = 64 rows x 32 cols; m-iters of 512 rows.
template <bool WFRAG>
__global__ __launch_bounds__(512) void k_logit3(
    const u16* __restrict__ Af, int fragBase,
    const u16* __restrict__ Wf, const float* __restrict__ Wraw,
    const float* __restrict__ bias, float* __restrict__ outp,
    int mStart, int mEnd, int storeLo, int storeHi, int skipLo, int skipHi) {
  __shared__ u16 wpan[32768];  // [fr(2)][kblk(32)][512]
  int nb = blockIdx.x;
  int tid = threadIdx.x;
  if constexpr (WFRAG) {
    const uint4* src = (const uint4*)(Wf + (size_t)nb * 32768);
    uint4* dst = (uint4*)wpan;
#pragma unroll
    for (int q = 0; q < 8; q++) dst[tid + q * 512] = src[tid + q * 512];
  } else {
    int wv = tid >> 6, l = tid & 63;
    for (int f = wv; f < 64; f += 8) {
      int fr = f >> 5, kb = f & 31;
      const float* src = Wraw + (size_t)(nb * 32 + fr * 16 + (l & 15)) * cH + kb * 32 + (l >> 4) * 8;
      *(short8*)(wpan + f * 512 + l * 8) = ldfragW(src);
    }
  }
  __syncthreads();
  int wave = tid >> 6, lane = tid & 63;
  int lr = lane & 15, kg = lane >> 4;
  for (int m0 = mStart; m0 < mEnd; m0 += 512) {
    int mi = m0 + wave * 64;
    int mfg[4];
#pragma unroll
    for (int mf = 0; mf < 4; mf++) {
      int g = (mi >> 4) + mf;
      if (g > 259) g = 259;
      mfg[mf] = g - fragBase;
    }
    floatx4 acc[4][2];
#pragma unroll
    for (int mf = 0; mf < 4; mf++)
#pragma unroll
      for (int ni = 0; ni < 2; ni++) acc[mf][ni] = (floatx4){0.f, 0.f, 0.f, 0.f};
#pragma unroll 4
    for (int ks = 0; ks < 32; ks++) {
      short8 bv0 = *(const short8*)(wpan + ks * 512 + lane * 8);
      short8 bv1 = *(const short8*)(wpan + (32 + ks) * 512 + lane * 8);
#pragma unroll
      for (int mf = 0; mf < 4; mf++) {
        short8 av = *(const short8*)(Af + ((size_t)mfg[mf] * 32 + ks) * 512 + lane * 8);
        acc[mf][0] = __builtin_amdgcn_mfma_f32_16x16x32_bf16(av, bv0, acc[mf][0], 0, 0, 0);
        acc[mf][1] = __builtin_amdgcn_mfma_f32_16x16x32_bf16(av, bv1, acc[mf][1], 0, 0, 0);
      }
    }
#pragma unroll
    for (int mf = 0; mf < 4; mf++) {
#pragma unroll
      for (int ni = 0; ni < 2; ni++) {
        int n = nb * 32 + ni * 16 + lr;
        float bb = bias[n];
#pragma unroll
        for (int jj = 0; jj < 4; jj++) {
          int m = mi + mf * 16 + kg * 4 + jj;
          if (m >= storeLo && m < storeHi && !(m >= skipLo && m < skipHi))
            outp[(size_t)m * cV + n] = acc[mf][ni][jj] + bb;
        }
      }
    }
  }
}

// ---- row log-softmax, 2-pass online ----
__global__ __launch_bounds__(256) void k_lsm(float* __restrict__ outp) {
  __shared__ float wm_[4], ws_[4];
  __shared__ float blz;
  int m = blockIdx.x;
  int tid = threadIdx.x, lane = tid & 63, wid = tid >> 6;
  float4* rp4 = (float4*)(outp + (size_t)m * cV);
  float mx = -INFINITY, sm = 0.f;
  for (int n = tid; n < cV / 4; n += 256) {
    float4 v = rp4[n];
    float lm = fmaxf(fmaxf(v.x, v.y), fmaxf(v.z, v.w));
    float nm = fmaxf(mx, lm);
    sm = sm * expf(mx - nm) + expf(v.x - nm) + expf(v.y - nm) + expf(v.z - nm) + expf(v.w - nm);
    mx = nm;
  }
#pragma unroll
  for (int off = 32; off >= 1; off >>= 1) {
    float om = __shfl_xor(mx, off), os = __shfl_xor(sm, off);
    float nm = fmaxf(mx, om);
    sm = sm * expf(mx - nm) + os * expf(om - nm);
    mx = nm;
  }
  if (lane == 0) { wm_[wid] = mx; ws_[wid] = sm; }
  __syncthreads();
  if (tid == 0) {
    float M = fmaxf(fmaxf(wm_[0], wm_[1]), fmaxf(wm_[2], wm_[3]));
    float S = ws_[0] * expf(wm_[0] - M) + ws_[1] * expf(wm_[1] - M) +
              ws_[2] * expf(wm_[2] - M) + ws_[3] * expf(wm_[3] - M);
    blz = M + logf(S);
  }
  __syncthreads();
  float lz = blz;
  for (int n = tid; n < cV / 4; n += 256) {
    float4 v = rp4[n];
    v.x -= lz; v.y -= lz; v.z -= lz; v.w -= lz;
    rp4[n] = v;
  }
}

extern "C" void kernel_launch(void* const* d_in, const int* in_sizes, int n_in,
                              void* d_out, int out_size, void* d_ws, size_t ws_size,
                              hipStream_t stream) {
  (void)in_sizes; (void)n_in; (void)out_size; (void)ws_size;
  const int* enc_input  = (const int*)d_in[0];
  const int* dec_input  = (const int*)d_in[1];
  const int* length     = (const int*)d_in[2];
  const float* eps      = (const float*)d_in[3];
  const float* enc_emb  = (const float*)d_in[4];
  const float* enc_Wih  = (const float*)d_in[5];
  const float* enc_Whh  = (const float*)d_in[6];
  const float* enc_bih  = (const float*)d_in[7];
  const float* enc_bhh  = (const float*)d_in[8];
  const float* latent_W = (const float*)d_in[9];
  const float* latent_b = (const float*)d_in[10];
  const float* dec_emb  = (const float*)d_in[11];
  const float* attn_W   = (const float*)d_in[12];
  const float* attn_b   = (const float*)d_in[13];
  const float* comb_W   = (const float*)d_in[14];
  const float* comb_b   = (const float*)d_in[15];
  const float* dec_Wih  = (const float*)d_in[16];
  const float* dec_Whh  = (const float*)d_in[17];
  const float* dec_bih  = (const float*)d_in[18];
  const float* dec_bhh  = (const float*)d_in[19];
  const float* pri_W    = (const float*)d_in[20];
  const float* pri_b    = (const float*)d_in[21];
  const float* inf_W    = (const float*)d_in[22];
  const float* inf_b    = (const float*)d_in[23];
  const float* aux_W    = (const float*)d_in[24];
  const float* aux_b    = (const float*)d_in[25];
  const float* out_W    = (const float*)d_in[26];
  const float* out_b    = (const float*)d_in[27];
  float* outp = (float*)d_out;
  float* outF = outp;

  // ---- scratch layout in logp head (dead before k_logit3) ----
  size_t off = 0;
  float* c_enc = outF + off; off += 65536;
  float* c_dec = outF + off; off += 65536;
  float* scal  = outF + off; off += 4;
  off += 60;
  u16* HfEncA = (u16*)(outF + off); off += 32768;
  u16* HfDecA = (u16*)(outF + off); off += 32768;
  u16* Hh     = (u16*)(outF + off); off += 66 * 32768;  // row-major [66][64][1024]
  size_t zeroSpan = 229440;  // c_enc..Hh[0] inclusive
  u16* HfEncB = (u16*)(outF + off); off += 32768;
  u16* HfDecB = (u16*)(outF + off); off += 32768;
  u16* encO  = (u16*)(outF + off); off += 2097152;
  u16* Xenc  = (u16*)(outF + off); off += 1048576;
  u16* Xdec  = (u16*)(outF + off); off += 1064960;
  u16* zbuf  = (u16*)(outF + off); off += 4096;
  float* mulv  = outF + off; off += 16384;
  float* biasE = outF + off; off += 4096;
  float* biasD = outF + off; off += 4096;
  float* tmp1  = outF + off; off += 1024;
  float* u0    = outF + off; off += 1024;
  float* WcxT  = outF + off; off += 524288;
  float* WczT  = outF + off; off += 131072;
  float* wPmT  = outF + off; off += 131072;
  float* auxWT = outF + off; off += 131072;
  float* M1    = outF + off; off += 131072;
  float* WfT   = outF + off; off += 1048576;
  u16* WhhEpF = (u16*)(outF + off); off += 2097152;  // frag
  u16* WbigF  = (u16*)(outF + off); off += 2097152;  // frag
  u16* C1f    = (u16*)(outF + off); off += 1048576;  // frag KB=16
  u16* C2f    = (u16*)(outF + off); off += 262144;   // frag KB=4
  u16* WihEf  = (u16*)(outF + off); off += 1048576;  // frag KB=16
  u16* Genc  = (u16*)(outF + off); off += 8388608;
  u16* Gdec  = (u16*)(outF + off); off += 8519680;
  float* priH = outF + off; off += 1064960;
  float* infH = outF + off; off += 1064960;
  float* S    = outF + off; off += 266240;
  u16* ctxH  = (u16*)(outF + off); off += 2129920;
  u16* auxH  = (u16*)(outF + off); off += 2129920;  // ends ~38.88M < 39.94M
  u16* Wf   = (u16*)(outF + WBOUT_OFF);   // frag bf16 out_W: logp rows [1248,1760)
  u16* Amat = (u16*)(outF + AMAT_OFF);    // frag bf16 A: logp tail
  u16* wsA = (u16*)d_ws;

  // ---- prep ----
  k_cvtW<<<16000, 256, 0, stream>>>(out_W, Wf);
  k_tr<<<dim3(16, 32), 256, 0, stream>>>(comb_W, 1792, 1024, WcxT);
  k_tr<<<dim3(4, 32), 256, 0, stream>>>(comb_W + 1664, 1792, 1024, WczT);
  k_tr<<<dim3(32, 4), 256, 0, stream>>>(pri_W, 1024, 128, wPmT);
  k_tr<<<dim3(4, 32), 256, 0, stream>>>(aux_W, 128, 1024, auxWT);
  k_gemv<<<4, 256, 0, stream>>>(aux_W, 128, pri_b, aux_b, tmp1, 128, 0);
  k_gemv<<<4, 256, 0, stream>>>(comb_W + 512, 1792, tmp1, comb_b, u0, 1024, 0);
  k_gemv<<<4, 256, 0, stream>>>(comb_W + 1536, 1792, pri_b, nullptr, u0, 128, 1);
  k_biasE<<<16, 256, 0, stream>>>(enc_bih, enc_bhh, biasE);
  k_biasD<<<16, 256, 0, stream>>>(dec_bih, dec_bhh, dec_Wih, u0, biasD);
  k_packP<<<2048, 256, 0, stream>>>(enc_Whh, WhhEpF, 1024);
  k_packP<<<1024, 256, 0, stream>>>(enc_Wih, WihEf, 512);
  k_gather<<<cT * cB, 256, 0, stream>>>(enc_input, enc_emb, Xenc, cT);
  k_gather<<<cTP1 * cB, 256, 0, stream>>>(dec_input, dec_emb, Xdec, cTP1);
  k_zero<<<(int)((zeroSpan + 255) / 256), 256, 0, stream>>>(c_enc, (int)zeroSpan);

  // ---- weight composition ----
  k_gemm<float, float, float, 0, 0, false><<<dim3(8, 16), 64, 0, stream>>>(
      comb_W + 512, 1792, auxWT, 1024, nullptr, comb_W + 1536, 1792, M1, 128, 1024);
  k_gemm<float, float, float, 0, 0, false><<<dim3(64, 16), 64, 0, stream>>>(
      wPmT, 128, M1, 128, nullptr, nullptr, 0, WfT, 1024, 128);
  k_gemm<float, float, u16, 1, 0, false, 0, true><<<dim3(64, 64), 64, 0, stream>>>(
      dec_Wih, 1024, WfT, 1024, nullptr, dec_Whh, 1024, WbigF, 1024, 1024);
  k_gemm<float, float, u16, 1, 0, false, 0, true><<<dim3(32, 64), 64, 0, stream>>>(
      dec_Wih, 1024, WcxT, 1024, nullptr, nullptr, 0, C1f, 512, 1024);
  k_gemm<float, float, u16, 1, 0, false, 0, true><<<dim3(8, 64), 64, 0, stream>>>(
      dec_Wih, 1024, WczT, 1024, nullptr, nullptr, 0, C2f, 128, 1024);
  k_gemm<u16, u16, u16, 0, 0, false, 16, false><<<dim3(256, 64), 64, 0, stream>>>(
      Xenc, 512, WihEf, 512, biasE, nullptr, 0, Genc, 4096, 512);

  // ---- encoder loop ----
  for (int t = 0; t < cT; t++) {
    const u16* hin = (t & 1) ? HfEncB : HfEncA;
    u16* hout = (t & 1) ? HfEncA : HfEncB;
    k_cell3<<<256, 64, 0, stream>>>(Genc + (size_t)t * cB * 4096, hin, WhhEpF,
                                    c_enc, encO + (size_t)t * cH, cT * cH,
                                    hout, nullptr, 0);
  }
  k_latent<<<cB, 256, 0, stream>>>(encO, c_enc, latent_W, latent_b, mulv, outp);
  k_z<<<(cB * cZ + 255) / 256, 256, 0, stream>>>(mulv, eps, zbuf);

  // ---- Gdec ----
  k_gemm<u16, u16, u16, 0, 0, false, 16, false><<<dim3(256, 65), 64, 0, stream>>>(
      Xdec, 512, C1f, 512, biasD, nullptr, 0, Gdec, 4096, 512);
  k_gemm<u16, u16, u16, 2, 0, true, 4, false><<<dim3(256, 65), 64, 0, stream>>>(
      zbuf, 128, C2f, 128, nullptr, nullptr, 0, Gdec, 4096, 128);

  // ---- decoder loop ----
  for (int t = 0; t < cTP1; t++) {
    const u16* hin = (t & 1) ? HfDecB : HfDecA;
    u16* hout = (t & 1) ? HfDecA : HfDecB;
    k_cell3<<<256, 64, 0, stream>>>(Gdec + (size_t)t * cB * 4096, hin, WbigF,
                                    c_dec, Hh + (size_t)(t + 1) * cB * cH, cH,
                                    hout, Amat, t);
  }

  // ---- post-hoc batched math ----
  k_gemm<u16, float, float, 0, 0, false><<<dim3(16, 65), 64, 0, stream>>>(
      Hh, 1024, pri_W, 1024, pri_b, nullptr, 0, priH, 256, 1024);
  k_gemm<u16, float, float, 0, 0, false><<<dim3(4, 65), 64, 0, stream>>>(
      Xdec, 512, attn_W, 1536, attn_b, nullptr, 0, S, 64, 512);
  k_gemm<u16, float, float, 0, 0, true><<<dim3(4, 65), 64, 0, stream>>>(
      Hh, 1024, attn_W + 512, 1536, nullptr, nullptr, 0, S, 64, 1024);
  k_sctx<<<cTP1 * cB, 256, 0, stream>>>(S, enc_input, encO, ctxH);
  k_gemm<u16, float, float, 0, 0, false><<<dim3(16, 65), 64, 0, stream>>>(
      Hh, 1024, inf_W, 2048, inf_b, nullptr, 0, infH, 256, 1024);
  k_gemm<u16, float, float, 0, 0, true><<<dim3(16, 65), 64, 0, stream>>>(
      ctxH, 1024, inf_W + 1024, 2048, nullptr, nullptr, 0, infH, 256, 1024);
  k_gemm<float, float, u16, 0, 0, false><<<dim3(64, 65), 64, 0, stream>>>(
      priH, 256, aux_W, 128, aux_b, nullptr, 0, auxH, 1024, 128);
  k_scal_all<<<cTP1 * cB, 256, 0, stream>>>(priH, infH, ctxH, auxH, length, scal);
  k_scal<<<1, 64, 0, stream>>>(scal, outp);

  // ---- output projection + log-softmax ----
  k_cpyA<<<32, 256, 0, stream>>>(Amat, wsA);
  // L1: all rows, store m<4093 minus the Wf stripe; frag A + frag W panel (staged once)
  k_logit3<true><<<1000, 512, 0, stream>>>(Amat, 0, Wf, nullptr, out_b, outp,
                                           0, 4096, 0, 4093, SKIP_LO, SKIP_HI);
  // L2a: the stripe rows, W streamed from f32 original
  k_logit3<false><<<1000, 512, 0, stream>>>(Amat, 0, nullptr, out_W, out_b, outp,
                                            SKIP_LO, SKIP_HI, SKIP_LO, SKIP_HI, 0, 0);
  // L2b: tail rows from the d_ws frag copy
  k_logit3<false><<<1000, 512, 0, stream>>>(wsA, 252, nullptr, out_W, out_b, outp,
                                            4032, 4160, 4093, 4160, 0, 0);
  k_lsm<<<cB * cTP1, 256, 0, stream>>>(outp);
}